// Round 3
// baseline (327.011 us; speedup 1.0000x reference)
//
#include <hip/hip_runtime.h>
#include <math.h>

#define NBINS 80
#define NROT 16
#define NVERT 128
#define NRH 5

__global__ __launch_bounds__(64, 4) void masif_geo_conv(
    const float* __restrict__ rho_c,
    const float* __restrict__ th_c,
    const float* __restrict__ feat_g,
    const float* __restrict__ mask_g,
    const float* __restrict__ mu_rho,
    const float* __restrict__ sig_rho,
    const float* __restrict__ mu_th,
    const float* __restrict__ sig_th,
    const float* __restrict__ Wc,
    const float* __restrict__ bcv,
    float* __restrict__ out)
{
    const int n    = blockIdx.x;
    const int lane = threadIdx.x;
    const int t    = lane & 15;   // theta-bin index
    const int kq   = lane >> 4;   // k quad: k = 4*kq + s

    // union: phase-1 meta[128][12] (6144 B)  |  phase-2 desc[80][16] (5120 B)
    __shared__ float s_buf[NVERT * 12];
    __shared__ int   s_cnt;
    float (*s_meta)[12] = (float (*)[12])s_buf;
    float *s_desc = s_buf;

    constexpr float LOG2E  = 1.44269504088896340736f;
    constexpr float TWO_PI = 6.28318530717958647692f;
    constexpr float DLT    = TWO_PI / 16.0f;
    constexpr float EPSF   = 1e-5f;

    if (lane == 0) s_cnt = 0;
    __syncthreads();

    const float st = sig_th[0];
    const float Kt = -LOG2E / (st * st + EPSF);
    const float sr = sig_rho[0];
    const float Kr = -LOG2E / (sr * sr + EPSF);
    float mr[NRH];
    #pragma unroll
    for (int r = 0; r < NRH; ++r) mr[r] = mu_rho[r * 16];

    // ---- build compacted per-vertex table (masked verts dropped) ----
    for (int v = lane; v < NVERT; v += 64) {
        const float m = mask_g[n * NVERT + v];
        if (m != 0.0f) {
            const int pos = atomicAdd(&s_cnt, 1);
            const float th0 = th_c[n * NVERT + v];
            const float rho = rho_c[n * NVERT + v];
            int a = (int)floorf(th0 / DLT);
            a = a > 15 ? 15 : (a < 0 ? 0 : a);
            const float rv = th0 - (float)a * DLT;
            const float4 f4 = *(const float4*)&feat_g[(n * NVERT + v) * 4];
            s_meta[pos][0] = (float)a;
            s_meta[pos][1] = rv;
            s_meta[pos][2] = f4.x; s_meta[pos][3] = f4.y;
            s_meta[pos][4] = f4.z; s_meta[pos][5] = f4.w;
            #pragma unroll
            for (int r = 0; r < NRH; ++r) {
                const float dr = rho - mr[r];
                s_meta[pos][6 + r] = m * exp2f(Kr * dr * dr);
            }
        }
    }
    __syncthreads();
    const int nc = s_cnt;

    // ---- phase 1: accumulate num/den over compacted vertices ----
    float acc[4][NRH][4];   // [feat][rho][s]
    float den[NRH][4];
    #pragma unroll
    for (int r = 0; r < NRH; ++r)
        #pragma unroll
        for (int s = 0; s < 4; ++s) {
            den[r][s] = 0.0f;
            #pragma unroll
            for (int f = 0; f < 4; ++f) acc[f][r][s] = 0.0f;
        }

    for (int c = 0; c < nc; ++c) {
        const float4 m0 = *(const float4*)&s_meta[c][0];
        const float4 m1 = *(const float4*)&s_meta[c][4];
        const float4 m2 = *(const float4*)&s_meta[c][8];
        const int   jb = (int)m0.x + kq * 4;
        const float rv = m0.y;
        const float f0 = m0.z, f1 = m0.w, f2 = m1.x, f3 = m1.y;
        const float R[NRH] = {m1.z, m1.w, m2.x, m2.y, m2.z};

        float e[4];
        #pragma unroll
        for (int s = 0; s < 4; ++s) {
            const int j = (jb + s) & 15;
            const float dt = fmaf((float)(j - t), DLT, rv);
            e[s] = exp2f((Kt * dt) * dt);
        }
        #pragma unroll
        for (int r = 0; r < NRH; ++r)
            #pragma unroll
            for (int s = 0; s < 4; ++s) {
                const float tmp = R[r] * e[s];
                den[r][s] += tmp;
                acc[0][r][s] = fmaf(f0, tmp, acc[0][r][s]);
                acc[1][r][s] = fmaf(f1, tmp, acc[1][r][s]);
                acc[2][r][s] = fmaf(f2, tmp, acc[2][r][s]);
                acc[3][r][s] = fmaf(f3, tmp, acc[3][r][s]);
            }
    }

    // normalize accumulators in-place (den dies here)
    #pragma unroll
    for (int r = 0; r < NRH; ++r)
        #pragma unroll
        for (int s = 0; s < 4; ++s) {
            const float inv = 1.0f / (den[r][s] + EPSF);
            #pragma unroll
            for (int f = 0; f < 4; ++f) acc[f][r][s] *= inv;
        }

    // ---- phase 2: per feature i, stage desc_i (5 KB) then 80x80 matvec x16k ----
    for (int i = 0; i < 4; ++i) {
        __syncthreads();   // prior phase's desc reads (or meta reads) complete
        #pragma unroll
        for (int r = 0; r < NRH; ++r) {
            float4 d;
            d.x = acc[i][r][0]; d.y = acc[i][r][1];
            d.z = acc[i][r][2]; d.w = acc[i][r][3];
            // desc[bb][k]: bb = r*16+t, k = kq*4+s  -> fully contiguous b128 writes
            *(float4*)&s_desc[(r * 16 + t) * 16 + kq * 4] = d;
        }
        __syncthreads();

        #pragma unroll
        for (int p = 0; p < 5; ++p) {
            const int slot = p * 64 + lane;   // 320 slots = (cc, kq2)
            const int cc   = slot >> 2;
            const int kq2  = slot & 3;

            float c0 = 0.0f, c1 = 0.0f, c2 = 0.0f, c3 = 0.0f;
            const float* Wb = Wc + (size_t)i * NBINS * NBINS + cc;
            const float* db = &s_desc[kq2 * 4];
            for (int bb = 0; bb < NBINS; ++bb) {
                const float4 d4 = *(const float4*)&db[bb * 16];  // broadcast, conflict-free
                const float  w  = Wb[(size_t)bb * NBINS];        // 16 dwords/wave, coalesced
                c0 = fmaf(d4.x, w, c0);
                c1 = fmaf(d4.y, w, c1);
                c2 = fmaf(d4.z, w, c2);
                c3 = fmaf(d4.w, w, c3);
            }
            float mx = fmaxf(fmaxf(c0, c1), fmaxf(c2, c3));
            // max across the 4 lanes (kq2 groups) holding this cc
            mx = fmaxf(mx, __shfl_xor(mx, 1));
            mx = fmaxf(mx, __shfl_xor(mx, 2));
            if (kq2 == 0) {
                const float b = bcv[i * NBINS + cc];
                out[(size_t)n * 320 + i * NBINS + cc] = fmaxf(mx + b, 0.0f);
            }
        }
    }
}

extern "C" void kernel_launch(void* const* d_in, const int* in_sizes, int n_in,
                              void* d_out, int out_size, void* d_ws, size_t ws_size,
                              hipStream_t stream) {
    const float* rho   = (const float*)d_in[0];
    const float* theta = (const float*)d_in[1];
    const float* feat  = (const float*)d_in[2];
    const float* mask  = (const float*)d_in[3];
    const float* mu_r  = (const float*)d_in[4];
    const float* sg_r  = (const float*)d_in[5];
    const float* mu_t  = (const float*)d_in[6];
    const float* sg_t  = (const float*)d_in[7];
    const float* W     = (const float*)d_in[8];
    const float* bconv = (const float*)d_in[9];
    float* outp = (float*)d_out;

    const int nsamp = in_sizes[0] / NVERT;
    masif_geo_conv<<<nsamp, 64, 0, stream>>>(
        rho, theta, feat, mask, mu_r, sg_r, mu_t, sg_t, W, bconv, outp);
}

// Round 4
// 308.863 us; speedup vs baseline: 1.0588x; 1.0588x over previous
//
#include <hip/hip_runtime.h>
#include <math.h>

#define NBINS 80
#define NROT 16
#define NVERT 128
#define NRH 5

// One wave (64 threads) per sample. Wave-synchronous: no __syncthreads needed.
// NOTE R2 lesson: __launch_bounds__(64,4) made the compiler allocate 64 VGPRs
// and spill ~4.5 KB/block to scratch (FETCH +10MB, WRITE +18MB). Leave the
// register allocator unconstrained.
__global__ __launch_bounds__(64) void masif_geo_conv(
    const float* __restrict__ rho_c,
    const float* __restrict__ th_c,
    const float* __restrict__ feat_g,
    const float* __restrict__ mask_g,
    const float* __restrict__ mu_rho,
    const float* __restrict__ sig_rho,
    const float* __restrict__ mu_th,
    const float* __restrict__ sig_th,
    const float* __restrict__ Wc,
    const float* __restrict__ bcv,
    float* __restrict__ out)
{
    const int n    = blockIdx.x;
    const int lane = threadIdx.x;
    const int t    = lane & 15;   // theta-bin index
    const int kq   = lane >> 4;   // k quad: k = 4*kq + s

    // union: phase-1 meta[128][12] (6144 B)  |  phase-2 desc[80][16] (5120 B)
    __shared__ float s_buf[NVERT * 12];
    float (*s_meta)[12] = (float (*)[12])s_buf;
    float *s_desc = s_buf;

    constexpr float LOG2E  = 1.44269504088896340736f;
    constexpr float TWO_PI = 6.28318530717958647692f;
    constexpr float DLT    = TWO_PI / 16.0f;
    constexpr float EPSF   = 1e-5f;

    const float st = sig_th[0];
    const float Kt = -LOG2E / (st * st + EPSF);
    const float sr = sig_rho[0];
    const float Kr = -LOG2E / (sr * sr + EPSF);
    float mr[NRH];
    #pragma unroll
    for (int r = 0; r < NRH; ++r) mr[r] = mu_rho[r * 16];

    // ---- build compacted per-vertex table via ballot prefix (no atomics) ----
    int base = 0;
    #pragma unroll
    for (int v0 = 0; v0 < NVERT; v0 += 64) {
        const int v = v0 + lane;
        const float m = mask_g[n * NVERT + v];
        const bool act = (m != 0.0f);
        const unsigned long long bal = __ballot(act);
        if (act) {
            const int pos = base + (int)__popcll(bal & ((1ull << lane) - 1ull));
            const float th0 = th_c[n * NVERT + v];
            const float rho = rho_c[n * NVERT + v];
            int a = (int)floorf(th0 / DLT);
            a = a > 15 ? 15 : (a < 0 ? 0 : a);
            const float rv = th0 - (float)a * DLT;
            const float4 f4 = *(const float4*)&feat_g[(n * NVERT + v) * 4];
            s_meta[pos][0] = (float)a;
            s_meta[pos][1] = rv;
            s_meta[pos][2] = f4.x; s_meta[pos][3] = f4.y;
            s_meta[pos][4] = f4.z; s_meta[pos][5] = f4.w;
            #pragma unroll
            for (int r = 0; r < NRH; ++r) {
                const float dr = rho - mr[r];
                s_meta[pos][6 + r] = m * exp2f(Kr * dr * dr);
            }
        }
        base += (int)__popcll(bal);
    }
    const int nc = base;   // wave-uniform

    // ---- phase 1: accumulate num/den over compacted vertices ----
    float acc[4][NRH][4];   // [feat][rho][s]
    float den[NRH][4];
    #pragma unroll
    for (int r = 0; r < NRH; ++r)
        #pragma unroll
        for (int s = 0; s < 4; ++s) {
            den[r][s] = 0.0f;
            #pragma unroll
            for (int f = 0; f < 4; ++f) acc[f][r][s] = 0.0f;
        }

    for (int c = 0; c < nc; ++c) {
        const float4 m0 = *(const float4*)&s_meta[c][0];
        const float4 m1 = *(const float4*)&s_meta[c][4];
        const float4 m2 = *(const float4*)&s_meta[c][8];
        const int   jb = (int)m0.x + kq * 4;
        const float rv = m0.y;
        const float f0 = m0.z, f1 = m0.w, f2 = m1.x, f3 = m1.y;
        const float R[NRH] = {m1.z, m1.w, m2.x, m2.y, m2.z};

        float e[4];
        #pragma unroll
        for (int s = 0; s < 4; ++s) {
            const int j = (jb + s) & 15;
            const float dt = fmaf((float)(j - t), DLT, rv);
            e[s] = exp2f((Kt * dt) * dt);
        }
        #pragma unroll
        for (int r = 0; r < NRH; ++r)
            #pragma unroll
            for (int s = 0; s < 4; ++s) {
                const float tmp = R[r] * e[s];
                den[r][s] += tmp;
                acc[0][r][s] = fmaf(f0, tmp, acc[0][r][s]);
                acc[1][r][s] = fmaf(f1, tmp, acc[1][r][s]);
                acc[2][r][s] = fmaf(f2, tmp, acc[2][r][s]);
                acc[3][r][s] = fmaf(f3, tmp, acc[3][r][s]);
            }
    }

    // normalize accumulators in-place (den dies here)
    #pragma unroll
    for (int r = 0; r < NRH; ++r)
        #pragma unroll
        for (int s = 0; s < 4; ++s) {
            const float inv = 1.0f / (den[r][s] + EPSF);
            #pragma unroll
            for (int f = 0; f < 4; ++f) acc[f][r][s] *= inv;
        }

    // ---- phase 2: per feature i, stage desc_i (5 KB) then 80x80 matvec x16k ----
    for (int i = 0; i < 4; ++i) {
        #pragma unroll
        for (int r = 0; r < NRH; ++r) {
            float4 d;
            d.x = acc[i][r][0]; d.y = acc[i][r][1];
            d.z = acc[i][r][2]; d.w = acc[i][r][3];
            // desc[bb][k]: bb = r*16+t, k = kq*4+s  -> contiguous b128 writes
            *(float4*)&s_desc[(r * 16 + t) * 16 + kq * 4] = d;
        }
        // wave-synchronous: same wave wrote it, program order + lgkmcnt suffice

        #pragma unroll
        for (int p = 0; p < 5; ++p) {
            const int slot = p * 64 + lane;   // 320 slots = (cc, kq2)
            const int cc   = slot >> 2;
            const int kq2  = slot & 3;

            float c0 = 0.0f, c1 = 0.0f, c2 = 0.0f, c3 = 0.0f;
            const float* Wb = Wc + (size_t)i * NBINS * NBINS + cc;
            const float* db = &s_desc[kq2 * 4];
            #pragma unroll 4
            for (int bb = 0; bb < NBINS; ++bb) {
                const float4 d4 = *(const float4*)&db[bb * 16];  // 4 distinct addrs, conflict-free
                const float  w  = Wb[(size_t)bb * NBINS];        // 16 consecutive dwords/wave
                c0 = fmaf(d4.x, w, c0);
                c1 = fmaf(d4.y, w, c1);
                c2 = fmaf(d4.z, w, c2);
                c3 = fmaf(d4.w, w, c3);
            }
            float mx = fmaxf(fmaxf(c0, c1), fmaxf(c2, c3));
            // max across the 4 lanes (kq2 groups) holding this cc
            mx = fmaxf(mx, __shfl_xor(mx, 1));
            mx = fmaxf(mx, __shfl_xor(mx, 2));
            if (kq2 == 0) {
                const float b = bcv[i * NBINS + cc];
                out[(size_t)n * 320 + i * NBINS + cc] = fmaxf(mx + b, 0.0f);
            }
        }
    }
}

extern "C" void kernel_launch(void* const* d_in, const int* in_sizes, int n_in,
                              void* d_out, int out_size, void* d_ws, size_t ws_size,
                              hipStream_t stream) {
    const float* rho   = (const float*)d_in[0];
    const float* theta = (const float*)d_in[1];
    const float* feat  = (const float*)d_in[2];
    const float* mask  = (const float*)d_in[3];
    const float* mu_r  = (const float*)d_in[4];
    const float* sg_r  = (const float*)d_in[5];
    const float* mu_t  = (const float*)d_in[6];
    const float* sg_t  = (const float*)d_in[7];
    const float* W     = (const float*)d_in[8];
    const float* bconv = (const float*)d_in[9];
    float* outp = (float*)d_out;

    const int nsamp = in_sizes[0] / NVERT;
    masif_geo_conv<<<nsamp, 64, 0, stream>>>(
        rho, theta, feat, mask, mu_r, sg_r, mu_t, sg_t, W, bconv, outp);
}

// Round 5
// 202.770 us; speedup vs baseline: 1.6127x; 1.5232x over previous
//
#include <hip/hip_runtime.h>
#include <math.h>

#define NBINS 80
#define NROT 16
#define NVERT 128
#define NRH 5
#define AROW 104                 // descH row stride in halves (96 data + 8 pad)
#define WAVE_LDS_F 1600          // floats per wave slice (6400 B)
#define WS_BYTES (60 * 64 * 8 * 2)   // 60 frag-sets x 64 lanes x 8 halves

typedef _Float16 half8 __attribute__((ext_vector_type(8)));
typedef float f32x4 __attribute__((ext_vector_type(4)));

// ---- prep: W fp32 -> f16 MFMA B-fragments in d_ws ----
// entry e=(i*5+tile)*3+ks ; B[k][n]: n=lane&15 (cc in tile), k=(lane>>4)*8+j (bb in K-step)
__global__ __launch_bounds__(64) void prep_wfrag(const float* __restrict__ Wc,
                                                 _Float16* __restrict__ ws) {
    const int e    = blockIdx.x;
    const int lane = threadIdx.x;
    const int ks   = e % 3;
    const int tile = (e / 3) % 5;
    const int i    = e / 15;
    const int cc   = tile * 16 + (lane & 15);
    const int bb0  = ks * 32 + (lane >> 4) * 8;
    half8 h;
    #pragma unroll
    for (int j = 0; j < 8; ++j) {
        const int bb = bb0 + j;
        h[j] = (_Float16)((bb < NBINS) ? Wc[i * NBINS * NBINS + bb * NBINS + cc] : 0.0f);
    }
    *(half8*)(ws + ((size_t)e * 64 + lane) * 8) = h;
}

// One wave per sample, 4 waves (4 samples) per block. No barriers needed.
// R2/R3 lesson: no min-waves launch_bounds (spill); compiler parks acc in AGPRs.
__global__ __launch_bounds__(256) void masif_geo_conv(
    const float* __restrict__ rho_c,
    const float* __restrict__ th_c,
    const float* __restrict__ feat_g,
    const float* __restrict__ mask_g,
    const float* __restrict__ mu_rho,
    const float* __restrict__ sig_rho,
    const float* __restrict__ mu_th,
    const float* __restrict__ sig_th,
    const float* __restrict__ Wc,
    const float* __restrict__ bcv,
    const _Float16* __restrict__ ws,
    const int useWs,
    const int nsamp,
    float* __restrict__ out)
{
    const int wave = threadIdx.x >> 6;
    const int lane = threadIdx.x & 63;
    const int n    = blockIdx.x * 4 + wave;
    if (n >= nsamp) return;

    const int t  = lane & 15;   // theta-bin (phase 1)
    const int kq = lane >> 4;   // k quad (phase 1)

    __shared__ float s_buf[4 * WAVE_LDS_F];   // 25.6 KB
    float*      wbase  = s_buf + wave * WAVE_LDS_F;
    float     (*s_meta)[12] = (float (*)[12])wbase;        // 128*12 = 1536 f
    _Float16*   descH  = (_Float16*)wbase;                 // 16*104 halves = 832 f

    constexpr float LOG2E  = 1.44269504088896340736f;
    constexpr float TWO_PI = 6.28318530717958647692f;
    constexpr float DLT    = TWO_PI / 16.0f;
    constexpr float EPSF   = 1e-5f;

    const float st = sig_th[0];
    const float Kt = -LOG2E / (st * st + EPSF);
    const float sr = sig_rho[0];
    const float Kr = -LOG2E / (sr * sr + EPSF);
    float mr[NRH];
    #pragma unroll
    for (int r = 0; r < NRH; ++r) mr[r] = mu_rho[r * 16];

    // ---- compacted per-vertex table via ballot prefix ----
    int base = 0;
    #pragma unroll
    for (int v0 = 0; v0 < NVERT; v0 += 64) {
        const int v = v0 + lane;
        const float m = mask_g[n * NVERT + v];
        const bool act = (m != 0.0f);
        const unsigned long long bal = __ballot(act);
        if (act) {
            const int pos = base + (int)__popcll(bal & ((1ull << lane) - 1ull));
            const float th0 = th_c[n * NVERT + v];
            const float rho = rho_c[n * NVERT + v];
            int a = (int)floorf(th0 / DLT);
            a = a > 15 ? 15 : (a < 0 ? 0 : a);
            const float rv = th0 - (float)a * DLT;
            const float4 f4 = *(const float4*)&feat_g[(n * NVERT + v) * 4];
            s_meta[pos][0] = (float)a;
            s_meta[pos][1] = rv;
            s_meta[pos][2] = f4.x; s_meta[pos][3] = f4.y;
            s_meta[pos][4] = f4.z; s_meta[pos][5] = f4.w;
            #pragma unroll
            for (int r = 0; r < NRH; ++r) {
                const float dr = rho - mr[r];
                s_meta[pos][6 + r] = m * exp2f(Kr * dr * dr);
            }
        }
        base += (int)__popcll(bal);
    }
    const int nc = base;   // wave-uniform

    // ---- phase 1: accumulate num/den over compacted vertices ----
    float acc[4][NRH][4];   // [feat][rho][s]
    float den[NRH][4];
    #pragma unroll
    for (int r = 0; r < NRH; ++r)
        #pragma unroll
        for (int s = 0; s < 4; ++s) {
            den[r][s] = 0.0f;
            #pragma unroll
            for (int f = 0; f < 4; ++f) acc[f][r][s] = 0.0f;
        }

    for (int c = 0; c < nc; ++c) {
        const float4 m0 = *(const float4*)&s_meta[c][0];
        const float4 m1 = *(const float4*)&s_meta[c][4];
        const float4 m2 = *(const float4*)&s_meta[c][8];
        const int   jb = (int)m0.x + kq * 4;
        const float rv = m0.y;
        const float f0 = m0.z, f1 = m0.w, f2 = m1.x, f3 = m1.y;
        const float R[NRH] = {m1.z, m1.w, m2.x, m2.y, m2.z};

        float e[4];
        #pragma unroll
        for (int s = 0; s < 4; ++s) {
            const int j = (jb + s) & 15;
            const float dt = fmaf((float)(j - t), DLT, rv);
            e[s] = exp2f((Kt * dt) * dt);
        }
        #pragma unroll
        for (int r = 0; r < NRH; ++r)
            #pragma unroll
            for (int s = 0; s < 4; ++s) {
                const float tmp = R[r] * e[s];
                den[r][s] += tmp;
                acc[0][r][s] = fmaf(f0, tmp, acc[0][r][s]);
                acc[1][r][s] = fmaf(f1, tmp, acc[1][r][s]);
                acc[2][r][s] = fmaf(f2, tmp, acc[2][r][s]);
                acc[3][r][s] = fmaf(f3, tmp, acc[3][r][s]);
            }
    }

    // normalize in place
    #pragma unroll
    for (int r = 0; r < NRH; ++r)
        #pragma unroll
        for (int s = 0; s < 4; ++s) {
            const float inv = 1.0f / (den[r][s] + EPSF);
            #pragma unroll
            for (int f = 0; f < 4; ++f) acc[f][r][s] *= inv;
        }

    // ---- zero descH K-pad (bb 80..95 for all 16 k), once per sample ----
    // lane: k=lane&15, chunk=lane>>4 -> 4 halves (8B) each
    *(float2*)(descH + (lane & 15) * AROW + NBINS + (lane >> 4) * 4) = make_float2(0.0f, 0.0f);

    // ---- phase 2: per i, stage desc f16 (A-layout) then 15 MFMAs ----
    const half8* wsv = (const half8*)ws;
    #pragma unroll
    for (int i = 0; i < 4; ++i) {
        // stage: desc[k][bb] f16, k=kq*4+s, bb=r*16+t
        #pragma unroll
        for (int r = 0; r < NRH; ++r)
            #pragma unroll
            for (int s = 0; s < 4; ++s)
                descH[(kq * 4 + s) * AROW + r * 16 + t] = (_Float16)acc[i][r][s];

        f32x4 C[5];
        #pragma unroll
        for (int tile = 0; tile < 5; ++tile) C[tile] = (f32x4){0.f, 0.f, 0.f, 0.f};

        #pragma unroll
        for (int ks = 0; ks < 3; ++ks) {
            // A-frag: row m = lane&15 (k_rot), K-chunk j = (lane>>4)*8.. (bb)
            const half8 a = *(const half8*)(descH + (lane & 15) * AROW + ks * 32 + (lane >> 4) * 8);
            #pragma unroll
            for (int tile = 0; tile < 5; ++tile) {
                half8 b;
                if (useWs) {
                    b = wsv[(size_t)(((i * 5 + tile) * 3 + ks) * 64 + lane)];
                } else {
                    const int cc  = tile * 16 + (lane & 15);
                    const int bb0 = ks * 32 + (lane >> 4) * 8;
                    #pragma unroll
                    for (int j = 0; j < 8; ++j) {
                        const int bb = bb0 + j;
                        b[j] = (_Float16)((bb < NBINS) ? Wc[i * NBINS * NBINS + bb * NBINS + cc] : 0.0f);
                    }
                }
                C[tile] = __builtin_amdgcn_mfma_f32_16x16x32_f16(a, b, C[tile], 0, 0, 0);
            }
        }

        // C/D: col(cc-in-tile)=lane&15, row(k)=(lane>>4)*4+reg -> max over k
        float mx[5];
        #pragma unroll
        for (int tile = 0; tile < 5; ++tile) {
            float m = fmaxf(fmaxf(C[tile][0], C[tile][1]), fmaxf(C[tile][2], C[tile][3]));
            m = fmaxf(m, __shfl_xor(m, 16));
            m = fmaxf(m, __shfl_xor(m, 32));
            mx[tile] = m;
        }
        if (lane < 16) {
            #pragma unroll
            for (int tile = 0; tile < 5; ++tile) {
                const int cc = tile * 16 + lane;
                out[(size_t)n * 320 + i * NBINS + cc] =
                    fmaxf(mx[tile] + bcv[i * NBINS + cc], 0.0f);
            }
        }
    }
}

extern "C" void kernel_launch(void* const* d_in, const int* in_sizes, int n_in,
                              void* d_out, int out_size, void* d_ws, size_t ws_size,
                              hipStream_t stream) {
    const float* rho   = (const float*)d_in[0];
    const float* theta = (const float*)d_in[1];
    const float* feat  = (const float*)d_in[2];
    const float* mask  = (const float*)d_in[3];
    const float* mu_r  = (const float*)d_in[4];
    const float* sg_r  = (const float*)d_in[5];
    const float* mu_t  = (const float*)d_in[6];
    const float* sg_t  = (const float*)d_in[7];
    const float* W     = (const float*)d_in[8];
    const float* bconv = (const float*)d_in[9];
    float* outp = (float*)d_out;

    const int nsamp = in_sizes[0] / NVERT;
    const int useWs = (ws_size >= (size_t)WS_BYTES) ? 1 : 0;
    _Float16* wsh = (_Float16*)d_ws;

    if (useWs) prep_wfrag<<<60, 64, 0, stream>>>(W, wsh);

    masif_geo_conv<<<(nsamp + 3) / 4, 256, 0, stream>>>(
        rho, theta, feat, mask, mu_r, sg_r, mu_t, sg_t, W, bconv,
        wsh, useWs, nsamp, outp);
}

// Round 6
// 190.440 us; speedup vs baseline: 1.7171x; 1.0647x over previous
//
#include <hip/hip_runtime.h>
#include <math.h>

#define NBINS 80
#define NROT 16
#define NVERT 128
#define NRH 5

#define PSTRIDE 136          // halves per P row (272 B, 16B-mult, bank-spread)
#define GSTRIDE 34           // halves per g row (68 B -> quads on disjoint banks)
#define DSTRIDE 80           // halves per desc row (no pad; overread hits W zeros)
#define SLICE   19984        // bytes per wave slice (16B multiple)
#define OFF_P   0            // 25*136*2 = 6800 B
#define OFF_RV  6800         // 128 f32  =  512 B
#define OFF_A   7312         // 128 i16  =  256 B
#define OFF_G   7568         // 32*34*2  = 2176 B (per-chunk g table)
#define OFF_D   9744         // 4*16*80*2 = 10240 B (desc, all 4 feats)
#define WS_BYTES (60 * 64 * 8 * 2)

typedef _Float16 half8 __attribute__((ext_vector_type(8)));
typedef float f32x4 __attribute__((ext_vector_type(4)));

// ---- prep: W fp32 -> f16 MFMA B-fragments in d_ws (zeros for bb>=80!) ----
__global__ __launch_bounds__(64) void prep_wfrag(const float* __restrict__ Wc,
                                                 _Float16* __restrict__ ws) {
    const int e    = blockIdx.x;
    const int lane = threadIdx.x;
    const int ks   = e % 3;
    const int tile = (e / 3) % 5;
    const int i    = e / 15;
    const int cc   = tile * 16 + (lane & 15);
    const int bb0  = ks * 32 + (lane >> 4) * 8;
    half8 h;
    #pragma unroll
    for (int j = 0; j < 8; ++j) {
        const int bb = bb0 + j;
        h[j] = (_Float16)((bb < NBINS) ? Wc[i * NBINS * NBINS + bb * NBINS + cc] : 0.0f);
    }
    *(half8*)(ws + ((size_t)e * 64 + lane) * 8) = h;
}

// One wave per sample, 2 waves per block, no barriers (per-wave LDS slices).
__global__ __launch_bounds__(128) void masif_geo_conv(
    const float* __restrict__ rho_c,
    const float* __restrict__ th_c,
    const float* __restrict__ feat_g,
    const float* __restrict__ mask_g,
    const float* __restrict__ mu_rho,
    const float* __restrict__ sig_rho,
    const float* __restrict__ mu_th,
    const float* __restrict__ sig_th,
    const float* __restrict__ Wc,
    const float* __restrict__ bcv,
    const _Float16* __restrict__ ws,
    const int useWs,
    const int nsamp,
    float* __restrict__ out)
{
    const int wave = threadIdx.x >> 6;
    const int lane = threadIdx.x & 63;
    const int n    = blockIdx.x * 2 + wave;
    if (n >= nsamp) return;

    const int t  = lane & 15;
    const int kq = lane >> 4;

    __shared__ __align__(16) char s_raw[2 * SLICE + 64];  // +64: A-frag overread pad
    char* slice = s_raw + wave * SLICE;
    _Float16* s_P  = (_Float16*)(slice + OFF_P);
    float*    s_rv = (float*)(slice + OFF_RV);
    short*    s_a  = (short*)(slice + OFF_A);
    _Float16* s_g  = (_Float16*)(slice + OFF_G);
    _Float16* s_d  = (_Float16*)(slice + OFF_D);

    constexpr float LOG2E   = 1.44269504088896340736f;
    constexpr float TWO_PI  = 6.28318530717958647692f;
    constexpr float DLT     = TWO_PI / 16.0f;
    constexpr float INV_DLT = 16.0f / TWO_PI;
    constexpr float EPSF    = 1e-5f;

    // ---- prefill: P=0, rv=1e30 (-> g=exp2(-inf)=0), a=0 ----
    #pragma unroll
    for (int x = 0; x < 7; ++x) {
        const int idx = x * 64 + lane;
        if (idx < 425) ((int4*)s_P)[idx] = make_int4(0, 0, 0, 0);
    }
    s_rv[lane]      = 1e30f;
    s_rv[64 + lane] = 1e30f;
    ((int*)s_a)[lane] = 0;

    const float st = sig_th[0];
    const float Kt = -LOG2E / (st * st + EPSF);
    const float sr = sig_rho[0];
    const float Kr = -LOG2E / (sr * sr + EPSF);
    float mr[NRH];
    #pragma unroll
    for (int r = 0; r < NRH; ++r) mr[r] = mu_rho[r * 16];

    // ---- compaction: build P rows, rv, a (masked verts dropped) ----
    // P row map: (f,r<4)->f*4+r ; (f,r=4)->16+f ; den r->20+r
    int base = 0;
    #pragma unroll
    for (int v0 = 0; v0 < NVERT; v0 += 64) {
        const int v = v0 + lane;
        const float m = mask_g[n * NVERT + v];
        const bool act = (m != 0.0f);
        const unsigned long long bal = __ballot(act);
        if (act) {
            const int pos = base + (int)__popcll(bal & ((1ull << lane) - 1ull));
            const float th0 = th_c[n * NVERT + v];
            const float rho = rho_c[n * NVERT + v];
            int aa = (int)floorf(th0 * INV_DLT);
            aa = aa > 15 ? 15 : (aa < 0 ? 0 : aa);
            s_rv[pos] = th0 - (float)aa * DLT;
            s_a[pos]  = (short)aa;
            const float4 f4 = *(const float4*)&feat_g[(n * NVERT + v) * 4];
            float R[NRH];
            #pragma unroll
            for (int r = 0; r < NRH; ++r) {
                const float dr = rho - mr[r];
                R[r] = m * exp2f(Kr * dr * dr);
            }
            const float fv[4] = {f4.x, f4.y, f4.z, f4.w};
            #pragma unroll
            for (int f = 0; f < 4; ++f) {
                #pragma unroll
                for (int r = 0; r < 4; ++r)
                    s_P[(f * 4 + r) * PSTRIDE + pos] = (_Float16)(fv[f] * R[r]);
                s_P[(16 + f) * PSTRIDE + pos] = (_Float16)(fv[f] * R[4]);
            }
            #pragma unroll
            for (int r = 0; r < NRH; ++r)
                s_P[(20 + r) * PSTRIDE + pos] = (_Float16)R[r];
        }
        base += (int)__popcll(bal);
    }

    // ---- phase 1: num/den = P[25x128] @ E[128x256] via MFMA, K-blocked by 32 ----
    f32x4 C0[16], C1[16];
    #pragma unroll
    for (int nt = 0; nt < 16; ++nt) {
        C0[nt] = (f32x4){0.f, 0.f, 0.f, 0.f};
        C1[nt] = (f32x4){0.f, 0.f, 0.f, 0.f};
    }

    int gb[8];   // per-lane constant gather offsets (halves)
    #pragma unroll
    for (int j = 0; j < 8; ++j) gb[j] = (kq * 8 + j) * GSTRIDE + (15 - t);

    for (int ch = 0; ch < 4; ++ch) {
        // build g-table for this chunk's 32 verts (2 verts / iter, 32 cols each)
        #pragma unroll
        for (int it = 0; it < 16; ++it) {
            const int cl = it * 2 + (lane >> 5);
            const float rv = s_rv[ch * 32 + cl];
            const float dt = fmaf((float)((lane & 31) - 15), DLT, rv);
            s_g[cl * GSTRIDE + (lane & 31)] = (_Float16)exp2f(Kt * dt * dt);
        }
        // A-frags from P for this K-chunk (m = lane&15 -> P row; tile1 rows 16+)
        const half8 a0 = *(const half8*)(s_P + t * PSTRIDE + ch * 32 + kq * 8);
        const half8 a1 = *(const half8*)(s_P + (16 + t) * PSTRIDE + ch * 32 + kq * 8);
        int av[8];
        #pragma unroll
        for (int j = 0; j < 8; ++j) av[j] = s_a[ch * 32 + kq * 8 + j];

        #pragma unroll
        for (int nt = 0; nt < 16; ++nt) {
            half8 b;   // B[k=c][n=t] = g_c[((a_c+nt)&15) - t + 15]
            #pragma unroll
            for (int j = 0; j < 8; ++j)
                b[j] = s_g[gb[j] + ((av[j] + nt) & 15)];
            C0[nt] = __builtin_amdgcn_mfma_f32_16x16x32_f16(a0, b, C0[nt], 0, 0, 0);
            C1[nt] = __builtin_amdgcn_mfma_f32_16x16x32_f16(a1, b, C1[nt], 0, 0, 0);
        }
    }

    // ---- epilogue 1: desc = num/(den+eps) -> s_d[i][k][bb] f16 ----
    // D layout: col=lane&15 (=t), row=(lane>>4)*4+reg. den rows (P 20..24) =
    // tile1 local rows 4..8 -> quad1 regs 0..3 (r=0..3), quad2 reg0 (r=4).
    #pragma unroll
    for (int nt = 0; nt < 16; ++nt) {
        float den[5], inv[5];
        #pragma unroll
        for (int r = 0; r < 4; ++r) den[r] = __shfl(C1[nt][r], 16 + t);
        den[4] = __shfl(C1[nt][0], 32 + t);
        #pragma unroll
        for (int r = 0; r < NRH; ++r) {
            const float x = den[r] + EPSF;
            float v = __builtin_amdgcn_rcpf(x);
            inv[r] = v * (2.0f - x * v);   // 1 Newton step
        }
        // tile0 row 4*kq+reg -> (f=kq, r=reg): bb = reg*16+t
        #pragma unroll
        for (int reg = 0; reg < 4; ++reg)
            s_d[kq * 1280 + nt * DSTRIDE + reg * 16 + t] =
                (_Float16)(C0[nt][reg] * inv[reg]);
        // tile1 rows 0..3 (quad0 only) -> (f=reg, r=4): bb = 64+t
        if (kq == 0) {
            #pragma unroll
            for (int reg = 0; reg < 4; ++reg)
                s_d[reg * 1280 + nt * DSTRIDE + 64 + t] =
                    (_Float16)(C1[nt][reg] * inv[4]);
        }
    }

    // ---- phase 2: per i, conv[16k x 80cc] = desc @ W_i, max over k (R4-verified) ----
    const half8* wsv = (const half8*)ws;
    #pragma unroll
    for (int i = 0; i < 4; ++i) {
        f32x4 Cc[5];
        #pragma unroll
        for (int tile = 0; tile < 5; ++tile) Cc[tile] = (f32x4){0.f, 0.f, 0.f, 0.f};

        #pragma unroll
        for (int ks = 0; ks < 3; ++ks) {
            const half8 a = *(const half8*)(s_d + i * 1280 + t * DSTRIDE + ks * 32 + kq * 8);
            #pragma unroll
            for (int tile = 0; tile < 5; ++tile) {
                half8 b;
                if (useWs) {
                    b = wsv[(size_t)(((i * 5 + tile) * 3 + ks) * 64 + lane)];
                } else {
                    const int cc  = tile * 16 + t;
                    const int bb0 = ks * 32 + kq * 8;
                    #pragma unroll
                    for (int j = 0; j < 8; ++j) {
                        const int bb = bb0 + j;
                        b[j] = (_Float16)((bb < NBINS) ? Wc[i * NBINS * NBINS + bb * NBINS + cc] : 0.0f);
                    }
                }
                Cc[tile] = __builtin_amdgcn_mfma_f32_16x16x32_f16(a, b, Cc[tile], 0, 0, 0);
            }
        }

        #pragma unroll
        for (int tile = 0; tile < 5; ++tile) {
            float m = fmaxf(fmaxf(Cc[tile][0], Cc[tile][1]), fmaxf(Cc[tile][2], Cc[tile][3]));
            m = fmaxf(m, __shfl_xor(m, 16));
            m = fmaxf(m, __shfl_xor(m, 32));
            if (lane < 16) {
                const int cc = tile * 16 + lane;
                out[(size_t)n * 320 + i * NBINS + cc] =
                    fmaxf(m + bcv[i * NBINS + cc], 0.0f);
            }
        }
    }
}

extern "C" void kernel_launch(void* const* d_in, const int* in_sizes, int n_in,
                              void* d_out, int out_size, void* d_ws, size_t ws_size,
                              hipStream_t stream) {
    const float* rho   = (const float*)d_in[0];
    const float* theta = (const float*)d_in[1];
    const float* feat  = (const float*)d_in[2];
    const float* mask  = (const float*)d_in[3];
    const float* mu_r  = (const float*)d_in[4];
    const float* sg_r  = (const float*)d_in[5];
    const float* mu_t  = (const float*)d_in[6];
    const float* sg_t  = (const float*)d_in[7];
    const float* W     = (const float*)d_in[8];
    const float* bconv = (const float*)d_in[9];
    float* outp = (float*)d_out;

    const int nsamp = in_sizes[0] / NVERT;
    const int useWs = (ws_size >= (size_t)WS_BYTES) ? 1 : 0;
    _Float16* wsh = (_Float16*)d_ws;

    if (useWs) prep_wfrag<<<60, 64, 0, stream>>>(W, wsh);

    masif_geo_conv<<<(nsamp + 1) / 2, 128, 0, stream>>>(
        rho, theta, feat, mask, mu_r, sg_r, mu_t, sg_t, W, bconv,
        wsh, useWs, nsamp, outp);
}

// Round 7
// 182.586 us; speedup vs baseline: 1.7910x; 1.0430x over previous
//
#include <hip/hip_runtime.h>
#include <math.h>

#define NBINS 80
#define NVERT 128
#define NRH 5

#define PSTR 136       // halves: P/M row stride (272 B, 16B mult)
#define VSTR 32        // halves: V^T row stride (64 B)
#define DSTR 80        // halves: desc row stride (overread hits W zero rows)

// per-wave LDS slice (bytes)
#define OFF_VT 8704    // V^T: 128 rows x 32 halves = 8192 B   (P/M at 0: 32x136x2=8704)
#define OFF_U  16896   // u   f16 x 128 = 256 B
#define OFF_GM 17152   // gam f16 x 128 = 256 B
#define OFF_AA 17408   // a   i16 x 128 = 256 B
#define SLICE  17664   // desc (10240 B) overlays [0..10240) in epilogue/phase2

#define NSET_C 64      // C-matrix fragment sets (16 nt-tiles x 4 ksteps)
#define NSET_W 60      // W fragment sets (4 i x 5 tiles x 3 ksteps)
#define WS_BYTES ((NSET_C + NSET_W) * 64 * 8 * 2)

typedef _Float16 half8 __attribute__((ext_vector_type(8)));
typedef float f32x4 __attribute__((ext_vector_type(4)));

// ---- prep: build constant C-matrix frags + W frags in d_ws ----
// C[(a,d)][(nt,t)] = exp2(Kt*s^2) * z^d/d!,  s=((a+nt)&15 - t)*DLT + DLT/2,
// z = 2*ln2*Kt*s*(DLT/2)   (pairs with V[c][(a,d)] = gam * u^d, u = rv'/(DLT/2))
__global__ __launch_bounds__(64) void prep_frags(const float* __restrict__ Wc,
                                                 const float* __restrict__ sig_th,
                                                 _Float16* __restrict__ ws) {
    const int blk  = blockIdx.x;
    const int lane = threadIdx.x;
    constexpr float TWO_PI = 6.28318530717958647692f;
    constexpr float DLT    = TWO_PI / 16.0f;
    constexpr float LN2    = 0.69314718055994530942f;
    half8 h;
    if (blk < NSET_C) {
        constexpr float LOG2E = 1.44269504088896340736f;
        constexpr float EPSF  = 1e-5f;
        const float st = sig_th[0];
        const float Kt = -LOG2E / (st * st + EPSF);
        const int ks = blk & 3;
        const int nt = blk >> 2;
        const int t  = lane & 15;
        const int q  = lane >> 4;
        #pragma unroll
        for (int j = 0; j < 8; ++j) {
            const int k = ks * 32 + q * 8 + j;
            const int a = k >> 3;
            const int d = k & 7;
            const int m = ((a + nt) & 15) - t;
            const float s = fmaf((float)m, DLT, 0.5f * DLT);
            const float z = 2.0f * LN2 * Kt * s * (0.5f * DLT);
            float val = exp2f(Kt * s * s);
            for (int dd = 1; dd <= d; ++dd) val *= z / (float)dd;
            h[j] = (_Float16)val;
        }
    } else {
        const int e    = blk - NSET_C;
        const int ks   = e % 3;
        const int tile = (e / 3) % 5;
        const int i    = e / 15;
        const int cc   = tile * 16 + (lane & 15);
        const int bb0  = ks * 32 + (lane >> 4) * 8;
        #pragma unroll
        for (int j = 0; j < 8; ++j) {
            const int bb = bb0 + j;
            h[j] = (_Float16)((bb < NBINS) ? Wc[i * NBINS * NBINS + bb * NBINS + cc] : 0.0f);
        }
    }
    *(half8*)(ws + ((size_t)blk * 64 + lane) * 8) = h;
}

// One wave per sample, 2 waves per block, no barriers (disjoint LDS slices).
__global__ __launch_bounds__(128) void masif_geo_conv(
    const float* __restrict__ rho_c,
    const float* __restrict__ th_c,
    const float* __restrict__ feat_g,
    const float* __restrict__ mask_g,
    const float* __restrict__ mu_rho,
    const float* __restrict__ sig_rho,
    const float* __restrict__ mu_th,
    const float* __restrict__ sig_th,
    const float* __restrict__ Wc,
    const float* __restrict__ bcv,
    const _Float16* __restrict__ ws,
    const int useWs,
    const int nsamp,
    float* __restrict__ out)
{
    const int wave = threadIdx.x >> 6;
    const int lane = threadIdx.x & 63;
    const int n    = blockIdx.x * 2 + wave;
    if (n >= nsamp) return;

    const int t  = lane & 15;
    const int kq = lane >> 4;

    __shared__ __align__(16) char s_raw[2 * SLICE];
    char* slice = s_raw + wave * SLICE;
    _Float16* s_PM = (_Float16*)(slice);            // P (phase A) / M (phase B)
    _Float16* s_vt = (_Float16*)(slice + OFF_VT);   // V^T chunk buffer
    _Float16* s_u  = (_Float16*)(slice + OFF_U);
    _Float16* s_gm = (_Float16*)(slice + OFF_GM);
    short*    s_a  = (short*)(slice + OFF_AA);
    _Float16* s_d  = (_Float16*)(slice);            // desc (epilogue+phase2)

    constexpr float LOG2E   = 1.44269504088896340736f;
    constexpr float TWO_PI  = 6.28318530717958647692f;
    constexpr float DLT     = TWO_PI / 16.0f;
    constexpr float INV_DLT = 16.0f / TWO_PI;
    constexpr float EPSF    = 1e-5f;

    const float st = sig_th[0];
    const float Kt = -LOG2E / (st * st + EPSF);
    const float sr = sig_rho[0];
    const float Kr = -LOG2E / (sr * sr + EPSF);
    float mr[NRH];
    #pragma unroll
    for (int r = 0; r < NRH; ++r) mr[r] = mu_rho[r * 16];

    // ---- zero P (32 rows x 136 halves; rows 25..31 must be 0) ----
    #pragma unroll
    for (int x = 0; x < 9; ++x) {
        const int idx = x * 64 + lane;
        if (idx < 544) ((int4*)s_PM)[idx] = make_int4(0, 0, 0, 0);
    }

    // ---- compaction: P rows (f16), u, gam, a per active vertex ----
    int cbase = 0;
    #pragma unroll
    for (int v0 = 0; v0 < NVERT; v0 += 64) {
        const int v = v0 + lane;
        const float m = mask_g[n * NVERT + v];
        const bool act = (m != 0.0f);
        const unsigned long long bal = __ballot(act);
        if (act) {
            const int pos = cbase + (int)__popcll(bal & ((1ull << lane) - 1ull));
            const float th0 = th_c[n * NVERT + v];
            const float rho = rho_c[n * NVERT + v];
            int aa = (int)floorf(th0 * INV_DLT);
            aa = aa > 15 ? 15 : (aa < 0 ? 0 : aa);
            const float rvp = th0 - (float)aa * DLT - 0.5f * DLT;   // rv' in [-DLT/2, DLT/2)
            s_u[pos]  = (_Float16)(rvp * (2.0f * INV_DLT));         // u = rv'/(DLT/2)
            s_gm[pos] = (_Float16)exp2f(Kt * rvp * rvp);
            s_a[pos]  = (short)aa;
            const float4 f4 = *(const float4*)&feat_g[(n * NVERT + v) * 4];
            float R[NRH];
            #pragma unroll
            for (int r = 0; r < NRH; ++r) {
                const float dr = rho - mr[r];
                R[r] = m * exp2f(Kr * dr * dr);
            }
            const float fv[4] = {f4.x, f4.y, f4.z, f4.w};
            #pragma unroll
            for (int f = 0; f < 4; ++f) {
                #pragma unroll
                for (int r = 0; r < 4; ++r)
                    s_PM[(f * 4 + r) * PSTR + pos] = (_Float16)(fv[f] * R[r]);
                s_PM[(16 + f) * PSTR + pos] = (_Float16)(fv[f] * R[4]);
            }
            #pragma unroll
            for (int r = 0; r < NRH; ++r)
                s_PM[(20 + r) * PSTR + pos] = (_Float16)R[r];
        }
        cbase += (int)__popcll(bal);
    }
    const int nc = cbase;   // wave-uniform

    // ---- chain 1: M[25x128] = P[25x128c] @ V[128c x 128(a,d)], chunked by 32 c ----
    f32x4 M0[8], M1[8];
    #pragma unroll
    for (int ct = 0; ct < 8; ++ct) {
        M0[ct] = (f32x4){0.f, 0.f, 0.f, 0.f};
        M1[ct] = (f32x4){0.f, 0.f, 0.f, 0.f};
    }
    const int nch = (nc + 31) >> 5;
    for (int ch = 0; ch < nch; ++ch) {
        // zero V^T (128 x 32 halves = 8192 B)
        #pragma unroll
        for (int x = 0; x < 8; ++x)
            ((int4*)s_vt)[x * 64 + lane] = make_int4(0, 0, 0, 0);
        // build V^T entries: lane -> (cl = lane>>1, d-group = lane&1)
        {
            const int cl = lane >> 1;
            const int cg = ch * 32 + cl;
            if (cg < nc) {
                const float u = (float)s_u[cg];
                const float g = (float)s_gm[cg];
                const int   a = (int)s_a[cg];
                const int  d0 = (lane & 1) * 4;
                float p0, p1, p2, p3;
                if (d0 == 0) { p0 = 1.0f; p1 = u; p2 = u * u; p3 = p2 * u; }
                else { const float u2 = u * u, u4 = u2 * u2;
                       p0 = u4; p1 = u4 * u; p2 = u4 * u2; p3 = p2 * u; }
                const int bi = (a * 8 + d0) * VSTR + cl;
                s_vt[bi]            = (_Float16)(g * p0);
                s_vt[bi + VSTR]     = (_Float16)(g * p1);
                s_vt[bi + 2 * VSTR] = (_Float16)(g * p2);
                s_vt[bi + 3 * VSTR] = (_Float16)(g * p3);
            }
        }
        const half8 a0 = *(const half8*)(s_PM + t * PSTR + ch * 32 + kq * 8);
        const half8 a1 = *(const half8*)(s_PM + (16 + t) * PSTR + ch * 32 + kq * 8);
        #pragma unroll
        for (int ct = 0; ct < 8; ++ct) {
            const half8 b = *(const half8*)(s_vt + (ct * 16 + t) * VSTR + kq * 8);
            M0[ct] = __builtin_amdgcn_mfma_f32_16x16x32_f16(a0, b, M0[ct], 0, 0, 0);
            M1[ct] = __builtin_amdgcn_mfma_f32_16x16x32_f16(a1, b, M1[ct], 0, 0, 0);
        }
    }

    // ---- M -> LDS f16 in A-layout (overlays P; P dead). D: col=t, row=kq*4+reg ----
    #pragma unroll
    for (int ct = 0; ct < 8; ++ct) {
        const int md = ct * 16 + t;
        #pragma unroll
        for (int reg = 0; reg < 4; ++reg) {
            s_PM[(kq * 4 + reg) * PSTR + md]        = (_Float16)M0[ct][reg];
            s_PM[(16 + kq * 4 + reg) * PSTR + md]   = (_Float16)M1[ct][reg];
        }
    }

    // ---- chain 2: num[25 x 256(nt,t)] = M[25x128] @ C[128x256], B from const ws ----
    f32x4 C0[16], C1[16];
    #pragma unroll
    for (int nt = 0; nt < 16; ++nt) {
        C0[nt] = (f32x4){0.f, 0.f, 0.f, 0.f};
        C1[nt] = (f32x4){0.f, 0.f, 0.f, 0.f};
    }
    const half8* wsv = (const half8*)ws;
    #pragma unroll
    for (int ks = 0; ks < 4; ++ks) {
        const half8 a0 = *(const half8*)(s_PM + t * PSTR + ks * 32 + kq * 8);
        const half8 a1 = *(const half8*)(s_PM + (16 + t) * PSTR + ks * 32 + kq * 8);
        #pragma unroll
        for (int nt = 0; nt < 16; ++nt) {
            half8 b;
            if (useWs) {
                b = wsv[(size_t)((nt * 4 + ks) * 64 + lane)];
            } else {
                #pragma unroll
                for (int j = 0; j < 8; ++j) {
                    const int k = ks * 32 + kq * 8 + j;
                    const int a = k >> 3, d = k & 7;
                    const int m = ((a + nt) & 15) - t;
                    const float s = fmaf((float)m, DLT, 0.5f * DLT);
                    const float z = 2.0f * 0.69314718055994530942f * Kt * s * (0.5f * DLT);
                    float val = exp2f(Kt * s * s);
                    for (int dd = 1; dd <= d; ++dd) val *= z / (float)dd;
                    b[j] = (_Float16)val;
                }
            }
            C0[nt] = __builtin_amdgcn_mfma_f32_16x16x32_f16(a0, b, C0[nt], 0, 0, 0);
            C1[nt] = __builtin_amdgcn_mfma_f32_16x16x32_f16(a1, b, C1[nt], 0, 0, 0);
        }
    }

    // ---- epilogue 1 (R5-verified): desc = num/(den+eps) -> s_d[i][k][bb] f16 ----
    #pragma unroll
    for (int nt = 0; nt < 16; ++nt) {
        float den[5], inv[5];
        #pragma unroll
        for (int r = 0; r < 4; ++r) den[r] = __shfl(C1[nt][r], 16 + t);
        den[4] = __shfl(C1[nt][0], 32 + t);
        #pragma unroll
        for (int r = 0; r < NRH; ++r) {
            const float x = den[r] + EPSF;
            float v = __builtin_amdgcn_rcpf(x);
            inv[r] = v * (2.0f - x * v);
        }
        #pragma unroll
        for (int reg = 0; reg < 4; ++reg)
            s_d[kq * 1280 + nt * DSTR + reg * 16 + t] =
                (_Float16)(C0[nt][reg] * inv[reg]);
        if (kq == 0) {
            #pragma unroll
            for (int reg = 0; reg < 4; ++reg)
                s_d[reg * 1280 + nt * DSTR + 64 + t] =
                    (_Float16)(C1[nt][reg] * inv[4]);
        }
    }

    // ---- phase 2 (R4/R5-verified): per i, conv = desc @ W_i, max over k ----
    #pragma unroll
    for (int i = 0; i < 4; ++i) {
        f32x4 Cc[5];
        #pragma unroll
        for (int tile = 0; tile < 5; ++tile) Cc[tile] = (f32x4){0.f, 0.f, 0.f, 0.f};
        #pragma unroll
        for (int ks = 0; ks < 3; ++ks) {
            const half8 a = *(const half8*)(s_d + i * 1280 + t * DSTR + ks * 32 + kq * 8);
            #pragma unroll
            for (int tile = 0; tile < 5; ++tile) {
                half8 b;
                if (useWs) {
                    b = wsv[(size_t)((NSET_C + (i * 5 + tile) * 3 + ks) * 64 + lane)];
                } else {
                    const int cc  = tile * 16 + t;
                    const int bb0 = ks * 32 + kq * 8;
                    #pragma unroll
                    for (int j = 0; j < 8; ++j) {
                        const int bb = bb0 + j;
                        b[j] = (_Float16)((bb < NBINS) ? Wc[i * NBINS * NBINS + bb * NBINS + cc] : 0.0f);
                    }
                }
                Cc[tile] = __builtin_amdgcn_mfma_f32_16x16x32_f16(a, b, Cc[tile], 0, 0, 0);
            }
        }
        #pragma unroll
        for (int tile = 0; tile < 5; ++tile) {
            float m = fmaxf(fmaxf(Cc[tile][0], Cc[tile][1]), fmaxf(Cc[tile][2], Cc[tile][3]));
            m = fmaxf(m, __shfl_xor(m, 16));
            m = fmaxf(m, __shfl_xor(m, 32));
            if (lane < 16) {
                const int cc = tile * 16 + lane;
                out[(size_t)n * 320 + i * NBINS + cc] =
                    fmaxf(m + bcv[i * NBINS + cc], 0.0f);
            }
        }
    }
}

extern "C" void kernel_launch(void* const* d_in, const int* in_sizes, int n_in,
                              void* d_out, int out_size, void* d_ws, size_t ws_size,
                              hipStream_t stream) {
    const float* rho   = (const float*)d_in[0];
    const float* theta = (const float*)d_in[1];
    const float* feat  = (const float*)d_in[2];
    const float* mask  = (const float*)d_in[3];
    const float* mu_r  = (const float*)d_in[4];
    const float* sg_r  = (const float*)d_in[5];
    const float* mu_t  = (const float*)d_in[6];
    const float* sg_t  = (const float*)d_in[7];
    const float* W     = (const float*)d_in[8];
    const float* bconv = (const float*)d_in[9];
    float* outp = (float*)d_out;

    const int nsamp = in_sizes[0] / NVERT;
    const int useWs = (ws_size >= (size_t)WS_BYTES) ? 1 : 0;
    _Float16* wsh = (_Float16*)d_ws;

    if (useWs) prep_frags<<<NSET_C + NSET_W, 64, 0, stream>>>(W, sg_t, wsh);

    masif_geo_conv<<<(nsamp + 1) / 2, 128, 0, stream>>>(
        rho, theta, feat, mask, mu_r, sg_r, mu_t, sg_t, W, bconv,
        wsh, useWs, nsamp, outp);
}